// Round 6
// baseline (133.698 us; speedup 1.0000x reference)
//
#include <hip/hip_runtime.h>
#include <math.h>

// B=4, C=64, H=W=64 -> N=4096. fp32 in/out; fp16 MFMA internally.
// qkv: MFMA GEMM, x split hi/lo fp16; outputs bounced through LDS so ALL
//      global stores are coalesced 16B ushort8 (round-5 post-mortem: scattered
//      2-8B stores in (B,N,C) layout cost ~60us).
// Q is pre-scaled by log2(e) -> attn softmax uses native exp2f.
// attn: split-K flash; S^T = K*Q^T so softmax rows sit in lanes (q=col) and
// P^T stays in registers as the B-operand of 16x16x16 f16 MFMA.
#define T_N 4096
#define T_C 64
#define T_B 4
#define NSLICE 4
#define TILES_PER_SLICE (64 / NSLICE)
#define LOG2E 1.44269504088896340736f

typedef __attribute__((ext_vector_type(8))) _Float16 f16x8;  // 4 VGPRs
typedef __attribute__((ext_vector_type(4))) _Float16 f16x4;  // 2 VGPRs
typedef __attribute__((ext_vector_type(4))) float f32x4;     // MFMA acc

__device__ inline unsigned short f2h(float f) {
    union { _Float16 h; unsigned short s; } u; u.h = (_Float16)f; return u.s;
}
__device__ inline float h2f(unsigned short s) {
    union { unsigned short s; _Float16 h; } u; u.s = s; return (float)u.h;
}

// ---------------------------------------------------------------------------
// Kernel 1: QKV projection via MFMA. One projection per block (p=blockIdx.z).
// grid (N/64, B, 3) = 768 blocks, 256 thr (4 waves; wave = one 16-pixel subtile).
// D[n][o] = sum_c X[c][n] W[o][c] (+bias): A = x^T (hi/lo fp16, staged
// transposed in LDS), B = W (fp16). After MFMA, D is bounced through LDS
// (xsh/xsl reused) into the output layout and stored as coalesced ushort8.
//   p=0: qt_hi/qt_lo (B,N,C) scaled by log2e;  p=1: kt (B,N,C);  p=2: vb (B,C,N)
// ---------------------------------------------------------------------------
__global__ __launch_bounds__(256) void qkv_kernel(
    const float* __restrict__ x,
    const float* __restrict__ Wq, const float* __restrict__ bq,
    const float* __restrict__ Wk, const float* __restrict__ bk,
    const float* __restrict__ Wv, const float* __restrict__ bv,
    unsigned short* __restrict__ qt_hi, unsigned short* __restrict__ qt_lo,
    unsigned short* __restrict__ kt, unsigned short* __restrict__ vb)
{
    __shared__ __align__(16) unsigned short xsh[64 * 72];  // x^T hi / bounce 0
    __shared__ __align__(16) unsigned short xsl[64 * 72];  // x^T lo / bounce 1
    __shared__ __align__(16) unsigned short wf[64 * 72];   // W fp16: [o][ch]

    const int tid = threadIdx.x;
    const int n0  = blockIdx.x * 64;
    const int b   = blockIdx.y;
    const int p   = blockIdx.z;
    const float* W    = (p == 0) ? Wq : (p == 1) ? Wk : Wv;
    const float* bias = (p == 0) ? bq : (p == 1) ? bk : bv;
    const float* xb   = x + (size_t)b * T_C * T_N;

    // stage W -> fp16 LDS [o][c]
    for (int i = tid; i < 1024; i += 256) {
        const int o = i >> 4, c4 = (i & 15) * 4;
        const float4 w4 = ((const float4*)W)[i];
        f16x4 wh;
        wh[0] = (_Float16)w4.x; wh[1] = (_Float16)w4.y;
        wh[2] = (_Float16)w4.z; wh[3] = (_Float16)w4.w;
        *(f16x4*)&wf[o * 72 + c4] = wh;
    }
    // stage x -> hi/lo fp16, transposed [pixel][ch]
    for (int i = tid; i < 1024; i += 256) {
        const int c = i >> 4, nj4 = (i & 15) * 4;
        const float4 xv = *(const float4*)&xb[c * T_N + n0 + nj4];
        const float xa[4] = {xv.x, xv.y, xv.z, xv.w};
        #pragma unroll
        for (int j = 0; j < 4; ++j) {
            const unsigned short h = f2h(xa[j]);
            xsh[(nj4 + j) * 72 + c] = h;
            xsl[(nj4 + j) * 72 + c] = f2h(xa[j] - h2f(h));
        }
    }
    __syncthreads();

    const int wv_  = tid >> 6;      // wave = pixel subtile
    const int lane = tid & 63;
    const int quad = lane >> 4;
    const int col  = lane & 15;
    const size_t bN = (size_t)b * T_N;

    // A-frags: A[m=pixel][k=ch]: m=col -> pixel = wv_*16+col
    f16x8 xh[2], xl[2];
    #pragma unroll
    for (int s = 0; s < 2; ++s) {
        xh[s] = *(const f16x8*)&xsh[(wv_ * 16 + col) * 72 + s * 32 + quad * 8];
        xl[s] = *(const f16x8*)&xsl[(wv_ * 16 + col) * 72 + s * 32 + quad * 8];
    }
    __syncthreads();   // all fragment reads done before xsh/xsl reused as bounce

    #pragma unroll
    for (int osub = 0; osub < 4; ++osub) {
        f32x4 acc = (f32x4){0.f, 0.f, 0.f, 0.f};
        #pragma unroll
        for (int s = 0; s < 2; ++s) {
            // B[k=ch][n=o]: n=col -> o = osub*16+col
            const f16x8 wfr = *(const f16x8*)&wf[(osub * 16 + col) * 72 + s * 32 + quad * 8];
            acc = __builtin_amdgcn_mfma_f32_16x16x32_f16(xh[s], wfr, acc, 0, 0, 0);
            acc = __builtin_amdgcn_mfma_f32_16x16x32_f16(xl[s], wfr, acc, 0, 0, 0);
        }
        // acc[r]: pixel = wv_*16+quad*4+r, o = osub*16+col
        const float bb = bias[osub * 16 + col];
        if (p == 0) {           // bounce Q*log2e hi/lo as [pixel][o]
            #pragma unroll
            for (int r = 0; r < 4; ++r) {
                const float f = (acc[r] + bb) * LOG2E;
                const unsigned short h = f2h(f);
                const int a = (wv_ * 16 + quad * 4 + r) * 72 + osub * 16 + col;
                xsh[a] = h;
                xsl[a] = f2h(f - h2f(h));
            }
        } else if (p == 1) {    // bounce K as [pixel][o]
            #pragma unroll
            for (int r = 0; r < 4; ++r)
                xsh[(wv_ * 16 + quad * 4 + r) * 72 + osub * 16 + col] = f2h(acc[r] + bb);
        } else {                // bounce V as [o][pixel] (ushort4: r contiguous)
            union { ushort4 v; unsigned short s[4]; } hv;
            #pragma unroll
            for (int r = 0; r < 4; ++r) hv.s[r] = f2h(acc[r] + bb);
            *(ushort4*)&xsh[(osub * 16 + col) * 72 + wv_ * 16 + quad * 4] = hv.v;
        }
    }
    __syncthreads();   // p=2 bounce rows are cross-wave; uniform barrier

    // coalesced readback + 16B global stores
    if (p == 0) {
        #pragma unroll
        for (int h = 0; h < 2; ++h) {
            const int pix = wv_ * 16 + h * 8 + (lane >> 3);
            const int c8  = (lane & 7) * 8;
            *(f16x8*)&qt_hi[(bN + n0 + pix) * 64 + c8] = *(const f16x8*)&xsh[pix * 72 + c8];
            *(f16x8*)&qt_lo[(bN + n0 + pix) * 64 + c8] = *(const f16x8*)&xsl[pix * 72 + c8];
        }
    } else if (p == 1) {
        #pragma unroll
        for (int h = 0; h < 2; ++h) {
            const int pix = wv_ * 16 + h * 8 + (lane >> 3);
            const int c8  = (lane & 7) * 8;
            *(f16x8*)&kt[(bN + n0 + pix) * 64 + c8] = *(const f16x8*)&xsh[pix * 72 + c8];
        }
    } else {
        #pragma unroll
        for (int h = 0; h < 2; ++h) {
            const int c  = wv_ * 16 + h * 8 + (lane >> 3);
            const int p8 = (lane & 7) * 8;
            *(f16x8*)&vb[((size_t)(b * 64 + c)) * T_N + n0 + p8] =
                *(const f16x8*)&xsh[c * 72 + p8];
        }
    }
}

// ---------------------------------------------------------------------------
// Kernel 2: flash-attention partial over one key-slice.
// grid (64, NSLICE, B) = 1024 blocks, 256 thr (4 waves), LDS 18.4 KB ->
// 4 blocks/CU (16 waves/CU). S^T = K*Q^T (Q pre-scaled by log2e): softmax
// state per-lane scalar (2 cross-quad shuffles), exp2f throughout; P^T stays
// in registers as B-operand of mfma 16x16x16 f16 for O += V*P^T.
// ---------------------------------------------------------------------------
__global__ __launch_bounds__(256, 4) void attn_kernel(
    const unsigned short* __restrict__ qt_hi, const unsigned short* __restrict__ qt_lo,
    const unsigned short* __restrict__ kt, const unsigned short* __restrict__ vb,
    unsigned short* __restrict__ o_part, float* __restrict__ mp, float* __restrict__ lp)
{
    __shared__ __align__(16) unsigned short ks[64 * 72];   // [key][ch]
    __shared__ __align__(16) unsigned short vs[64 * 72];   // [ch][key]

    const int tid   = threadIdx.x;
    const int n0    = blockIdx.x * 64;
    const int slice = blockIdx.y;
    const int b     = blockIdx.z;
    const int wv_   = tid >> 6;
    const int lane  = tid & 63;
    const int quad  = lane >> 4;
    const int col   = lane & 15;

    const size_t bN = (size_t)b * T_N;
    const int q_own = n0 + wv_ * 16 + col;   // this lane's query

    // Q B-frags from global: B[k=ch][n=q]: n=col -> q_own, k=s*32+quad*8+j
    f16x8 qh[2], ql[2];
    #pragma unroll
    for (int s = 0; s < 2; ++s) {
        const size_t qoff = (bN + q_own) * 64 + s * 32 + quad * 8;
        qh[s] = *(const f16x8*)&qt_hi[qoff];
        ql[s] = *(const f16x8*)&qt_lo[qoff];
    }

    f32x4 O[4];
    #pragma unroll
    for (int t = 0; t < 4; ++t) O[t] = (f32x4){0.f, 0.f, 0.f, 0.f};
    float m_st = -INFINITY, l_st = 0.f;

    for (int it = 0; it < TILES_PER_SLICE; ++it) {
        const int m0 = (slice * TILES_PER_SLICE + it) * 64;
        __syncthreads();   // previous iteration's ks/vs reads done
        for (int i = tid; i < 1024; i += 256) {
            if (i < 512) {
                const int row = i >> 3, cc = i & 7;
                *(float4*)&ks[row * 72 + cc * 8] =
                    *(const float4*)&kt[(bN + m0 + row) * 64 + cc * 8];
            } else {
                const int j = i - 512, row = j >> 3, cc = j & 7;
                *(float4*)&vs[row * 72 + cc * 8] =
                    *(const float4*)&vb[((size_t)(b * 64 + row)) * T_N + m0 + cc * 8];
            }
        }
        __syncthreads();

        // --- S^T = K Q^T (log2-domain): acc[t] = S2[key=16t+quad*4+r][q=col] ---
        f32x4 acc[4];
        #pragma unroll
        for (int t = 0; t < 4; ++t) acc[t] = (f32x4){0.f, 0.f, 0.f, 0.f};
        #pragma unroll
        for (int s = 0; s < 2; ++s) {
            #pragma unroll
            for (int t = 0; t < 4; ++t) {
                const f16x8 kf =   // A[m=key][k=ch]: m=col -> key = 16t+col
                    *(const f16x8*)&ks[(t * 16 + col) * 72 + s * 32 + quad * 8];
                acc[t] = __builtin_amdgcn_mfma_f32_16x16x32_f16(kf, qh[s], acc[t], 0, 0, 0);
                acc[t] = __builtin_amdgcn_mfma_f32_16x16x32_f16(kf, ql[s], acc[t], 0, 0, 0);
            }
        }

        // --- online softmax (exp2): row = q = col; reduce across quads only ---
        float mx = -INFINITY;
        #pragma unroll
        for (int t = 0; t < 4; ++t)
            #pragma unroll
            for (int r = 0; r < 4; ++r) mx = fmaxf(mx, acc[t][r]);
        mx = fmaxf(mx, __shfl_xor(mx, 16));
        mx = fmaxf(mx, __shfl_xor(mx, 32));
        const float mnew = fmaxf(m_st, mx);
        const float alpha = exp2f(m_st - mnew);
        float sum = 0.f;
        f16x4 pf[4];
        #pragma unroll
        for (int t = 0; t < 4; ++t) {
            #pragma unroll
            for (int r = 0; r < 4; ++r) {
                const float pv = exp2f(acc[t][r] - mnew);
                sum += pv;
                pf[t][r] = (_Float16)pv;   // B[k=key=16t+quad*4+r][n=q=col]
            }
        }
        sum += __shfl_xor(sum, 16);
        sum += __shfl_xor(sum, 32);
        l_st = alpha * l_st + sum;
        m_st = mnew;

        // --- O = alpha*O + V P^T via 16x16x16 MFMA (P in registers) ---
        #pragma unroll
        for (int tc = 0; tc < 4; ++tc) {
            O[tc] *= alpha;
            #pragma unroll
            for (int t = 0; t < 4; ++t) {
                const f16x4 vf =   // A[m=c][k=key]: m=col -> c = tc*16+col
                    *(const f16x4*)&vs[(tc * 16 + col) * 72 + t * 16 + quad * 4];
                O[tc] = __builtin_amdgcn_mfma_f32_16x16x16f16(vf, pf[t], O[tc], 0, 0, 0);
            }
        }
    }

    // --- epilogue: O[tc][r]: c = tc*16+quad*4+r, q = col ---
    #pragma unroll
    for (int tc = 0; tc < 4; ++tc) {
        #pragma unroll
        for (int r = 0; r < 4; ++r) {
            o_part[((size_t)((slice * T_B + b) * 64 + tc * 16 + quad * 4 + r)) * T_N +
                   q_own] = f2h(O[tc][r]);
        }
    }
    if (quad == 0) {
        const size_t off = (size_t)(slice * T_B + b) * T_N + q_own;
        mp[off] = m_st;   // log2-domain
        lp[off] = l_st;
    }
}

// ---------------------------------------------------------------------------
// Kernel 3: combine slices (log2-domain m). grid (N/32, B), 256 thr.
// ---------------------------------------------------------------------------
__global__ __launch_bounds__(256) void combine_kernel(
    const unsigned short* __restrict__ o_part,
    const float* __restrict__ mp, const float* __restrict__ lp,
    float* __restrict__ out)
{
    __shared__ float wn[NSLICE][32];

    const int tid = threadIdx.x;
    const int n0  = blockIdx.x * 32;
    const int b   = blockIdx.y;

    if (tid < 32) {
        float m_s[NSLICE], l_s[NSLICE];
        #pragma unroll
        for (int s = 0; s < NSLICE; ++s) {
            const size_t off = (size_t)(s * T_B + b) * T_N + n0 + tid;
            m_s[s] = mp[off];
            l_s[s] = lp[off];
        }
        float M = m_s[0];
        #pragma unroll
        for (int s = 1; s < NSLICE; ++s) M = fmaxf(M, m_s[s]);
        float w_s[NSLICE], L = 0.f;
        #pragma unroll
        for (int s = 0; s < NSLICE; ++s) {
            w_s[s] = exp2f(m_s[s] - M);
            L += l_s[s] * w_s[s];
        }
        const float inv = 1.f / L;
        #pragma unroll
        for (int s = 0; s < NSLICE; ++s) wn[s][tid] = w_s[s] * inv;
    }
    __syncthreads();

    for (int t = tid; t < 512; t += 256) {
        const int c = t >> 3, g = t & 7;
        float4 acc = make_float4(0.f, 0.f, 0.f, 0.f);
        #pragma unroll
        for (int s = 0; s < NSLICE; ++s) {
            const ushort4 o4 = *(const ushort4*)
                &o_part[((size_t)((s * T_B + b) * 64 + c)) * T_N + n0 + g * 4];
            acc.x = fmaf(h2f(o4.x), wn[s][g * 4 + 0], acc.x);
            acc.y = fmaf(h2f(o4.y), wn[s][g * 4 + 1], acc.y);
            acc.z = fmaf(h2f(o4.z), wn[s][g * 4 + 2], acc.z);
            acc.w = fmaf(h2f(o4.w), wn[s][g * 4 + 3], acc.w);
        }
        *(float4*)&out[((size_t)(b * 64 + c)) * T_N + n0 + g * 4] = acc;
    }
}

// ---------------------------------------------------------------------------
extern "C" void kernel_launch(void* const* d_in, const int* in_sizes, int n_in,
                              void* d_out, int out_size, void* d_ws, size_t ws_size,
                              hipStream_t stream) {
    const float* x  = (const float*)d_in[0];
    const float* Wq = (const float*)d_in[1];
    const float* bq = (const float*)d_in[2];
    const float* Wk = (const float*)d_in[3];
    const float* bk = (const float*)d_in[4];
    const float* Wv = (const float*)d_in[5];
    const float* bv = (const float*)d_in[6];
    float* outp = (float*)d_out;

    const size_t elems = (size_t)T_B * T_N * T_C;
    unsigned short* qt_hi  = (unsigned short*)d_ws;
    unsigned short* qt_lo  = qt_hi + elems;
    unsigned short* ktp    = qt_lo + elems;
    unsigned short* vbuf   = ktp + elems;
    unsigned short* o_part = vbuf + elems;                       // NSLICE*elems
    float* mp = (float*)(o_part + (size_t)NSLICE * elems);
    float* lp = mp + (size_t)NSLICE * T_B * T_N;

    qkv_kernel<<<dim3(T_N / 64, T_B, 3), 256, 0, stream>>>(
        x, Wq, bq, Wk, bk, Wv, bv, qt_hi, qt_lo, ktp, vbuf);
    attn_kernel<<<dim3(T_N / 64, NSLICE, T_B), 256, 0, stream>>>(
        qt_hi, qt_lo, ktp, vbuf, o_part, mp, lp);
    combine_kernel<<<dim3(T_N / 32, T_B), 256, 0, stream>>>(
        o_part, mp, lp, outp);
}

// Round 7
// 129.728 us; speedup vs baseline: 1.0306x; 1.0306x over previous
//
#include <hip/hip_runtime.h>
#include <math.h>

// B=4, C=64, H=W=64 -> N=4096. fp32 in/out; fp16 MFMA internally.
// Precision: Q split hi/lo fp16 (exact products in fp32 acc); K/V/P fp16.
// R6 post-mortem: exp2f regressed attn (OCML precise path) -> __expf only.
// qkv: ONE fused kernel, x staged hi/lo once, all 3 W in LDS, MFMA GEMM,
// LDS-bounce epilogue, all global stores coalesced 16B.
#define T_N 4096
#define T_C 64
#define T_B 4
#define NSLICE 4
#define TILES_PER_SLICE (64 / NSLICE)

typedef __attribute__((ext_vector_type(8))) _Float16 f16x8;  // 4 VGPRs
typedef __attribute__((ext_vector_type(4))) _Float16 f16x4;  // 2 VGPRs
typedef __attribute__((ext_vector_type(4))) float f32x4;     // MFMA acc

__device__ inline unsigned short f2h(float f) {
    union { _Float16 h; unsigned short s; } u; u.h = (_Float16)f; return u.s;
}
__device__ inline float h2f(unsigned short s) {
    union { unsigned short s; _Float16 h; } u; u.s = s; return (float)u.h;
}

// ---------------------------------------------------------------------------
// Kernel 1: fused QKV projection via MFMA. grid (N/32, B) = 512 blocks,
// 256 thr (4 waves). LDS: x^T hi/lo (32px x 64ch, pitch 72) + 3 W fp16
// ([o][c], pitch 72) = 36 KB -> 2 blocks/CU by grid.
// Wave w: pixel subtile pst=(w&1)*16, osub pair oh=(w>>1)*2.
// Epilogues bounce D through LDS (x buffers reused) -> 16B coalesced stores.
//   qt_hi/qt_lo, kt: (B,N,C);  vb: (B,C,N)
// ---------------------------------------------------------------------------
__global__ __launch_bounds__(256) void qkv_kernel(
    const float* __restrict__ x,
    const float* __restrict__ Wq, const float* __restrict__ bq,
    const float* __restrict__ Wk, const float* __restrict__ bk,
    const float* __restrict__ Wv, const float* __restrict__ bv,
    unsigned short* __restrict__ qt_hi, unsigned short* __restrict__ qt_lo,
    unsigned short* __restrict__ kt, unsigned short* __restrict__ vb)
{
    __shared__ __align__(16) unsigned short xsh[32 * 72];   // x^T hi / bounce
    __shared__ __align__(16) unsigned short xsl[32 * 72];   // x^T lo / bounce
    __shared__ __align__(16) unsigned short wf[3][64 * 72]; // W fp16 [o][c]

    const int tid = threadIdx.x;
    const int n0  = blockIdx.x * 32;
    const int b   = blockIdx.y;
    const float* xb = x + (size_t)b * T_C * T_N;

    // stage all three W -> fp16 LDS [o][c]
    const float* Ws[3] = {Wq, Wk, Wv};
    #pragma unroll
    for (int p = 0; p < 3; ++p) {
        for (int i = tid; i < 1024; i += 256) {
            const int o = i >> 4, c4 = (i & 15) * 4;
            const float4 w4 = ((const float4*)Ws[p])[i];
            f16x4 wh;
            wh[0] = (_Float16)w4.x; wh[1] = (_Float16)w4.y;
            wh[2] = (_Float16)w4.z; wh[3] = (_Float16)w4.w;
            *(f16x4*)&wf[p][o * 72 + c4] = wh;
        }
    }
    // stage x -> hi/lo fp16, transposed [pixel][ch]
    for (int i = tid; i < 512; i += 256) {
        const int c = i >> 3, nj4 = (i & 7) * 4;
        const float4 xv = *(const float4*)&xb[c * T_N + n0 + nj4];
        const float xa[4] = {xv.x, xv.y, xv.z, xv.w};
        #pragma unroll
        for (int j = 0; j < 4; ++j) {
            const unsigned short h = f2h(xa[j]);
            xsh[(nj4 + j) * 72 + c] = h;
            xsl[(nj4 + j) * 72 + c] = f2h(xa[j] - h2f(h));
        }
    }
    __syncthreads();

    const int wv_  = tid >> 6;
    const int lane = tid & 63;
    const int quad = lane >> 4;
    const int col  = lane & 15;
    const int pst  = (wv_ & 1) * 16;      // pixel subtile base (0 or 16)
    const int oh   = (wv_ >> 1) * 2;      // osub base (0 or 2)
    const size_t bN = (size_t)b * T_N;

    // A-frags: A[m=pixel][k=ch]: m=col -> pixel = pst+col
    f16x8 xh[2], xl[2];
    #pragma unroll
    for (int s = 0; s < 2; ++s) {
        xh[s] = *(const f16x8*)&xsh[(pst + col) * 72 + s * 32 + quad * 8];
        xl[s] = *(const f16x8*)&xsl[(pst + col) * 72 + s * 32 + quad * 8];
    }
    __syncthreads();   // frags in registers; x buffers reusable as bounce

    const float* biases[3] = {bq, bk, bv};
    for (int p = 0; p < 3; ++p) {
        #pragma unroll
        for (int oo = 0; oo < 2; ++oo) {
            const int osub = oh + oo;
            f32x4 acc = (f32x4){0.f, 0.f, 0.f, 0.f};
            #pragma unroll
            for (int s = 0; s < 2; ++s) {
                // B[k=ch][n=o]: n=col -> o = osub*16+col
                const f16x8 wfr =
                    *(const f16x8*)&wf[p][(osub * 16 + col) * 72 + s * 32 + quad * 8];
                acc = __builtin_amdgcn_mfma_f32_16x16x32_f16(xh[s], wfr, acc, 0, 0, 0);
                acc = __builtin_amdgcn_mfma_f32_16x16x32_f16(xl[s], wfr, acc, 0, 0, 0);
            }
            // acc[r]: pixel = pst+quad*4+r, o = osub*16+col
            const float bb = biases[p][osub * 16 + col];
            if (p == 0) {           // Q hi/lo bounce as [pixel][o], pitch 72
                #pragma unroll
                for (int r = 0; r < 4; ++r) {
                    const float f = acc[r] + bb;
                    const unsigned short h = f2h(f);
                    const int a = (pst + quad * 4 + r) * 72 + osub * 16 + col;
                    xsh[a] = h;
                    xsl[a] = f2h(f - h2f(h));
                }
            } else if (p == 1) {    // K bounce as [pixel][o], pitch 72
                #pragma unroll
                for (int r = 0; r < 4; ++r)
                    xsh[(pst + quad * 4 + r) * 72 + osub * 16 + col] = f2h(acc[r] + bb);
            } else {                // V bounce as [o][pixel], pitch 36
                union { ushort4 v; unsigned short s[4]; } hv;
                #pragma unroll
                for (int r = 0; r < 4; ++r) hv.s[r] = f2h(acc[r] + bb);
                *(ushort4*)&xsh[(osub * 16 + col) * 36 + pst + quad * 4] = hv.v;
            }
        }
        __syncthreads();
        // coalesced readback + 16B global stores
        if (p == 0) {
            const int pix = tid >> 3, c8 = (tid & 7) * 8;
            *(f16x8*)&qt_hi[(bN + n0 + pix) * 64 + c8] = *(const f16x8*)&xsh[pix * 72 + c8];
            *(f16x8*)&qt_lo[(bN + n0 + pix) * 64 + c8] = *(const f16x8*)&xsl[pix * 72 + c8];
        } else if (p == 1) {
            const int pix = tid >> 3, c8 = (tid & 7) * 8;
            *(f16x8*)&kt[(bN + n0 + pix) * 64 + c8] = *(const f16x8*)&xsh[pix * 72 + c8];
        } else {
            const int o = tid >> 2, p8 = (tid & 3) * 8;
            *(f16x8*)&vb[((size_t)(b * 64 + o)) * T_N + n0 + p8] =
                *(const f16x8*)&xsh[o * 36 + p8];
        }
        if (p < 2) __syncthreads();   // before next p reuses bounce buffers
    }
}

// ---------------------------------------------------------------------------
// Kernel 2: flash-attention partial over one key-slice (R5 version, __expf).
// grid (64, NSLICE, B) = 1024 blocks, 256 thr (4 waves), LDS 18.4 KB ->
// 4 blocks/CU (16 waves/CU). S^T = K*Q^T: softmax state per-lane scalar
// (2 cross-quad shuffles); P^T stays in registers as B-operand of
// mfma 16x16x16 f16 for O += V*P^T.
// ---------------------------------------------------------------------------
__global__ __launch_bounds__(256, 4) void attn_kernel(
    const unsigned short* __restrict__ qt_hi, const unsigned short* __restrict__ qt_lo,
    const unsigned short* __restrict__ kt, const unsigned short* __restrict__ vb,
    unsigned short* __restrict__ o_part, float* __restrict__ mp, float* __restrict__ lp)
{
    __shared__ __align__(16) unsigned short ks[64 * 72];   // [key][ch]
    __shared__ __align__(16) unsigned short vs[64 * 72];   // [ch][key]

    const int tid   = threadIdx.x;
    const int n0    = blockIdx.x * 64;
    const int slice = blockIdx.y;
    const int b     = blockIdx.z;
    const int wv_   = tid >> 6;
    const int lane  = tid & 63;
    const int quad  = lane >> 4;
    const int col   = lane & 15;

    const size_t bN = (size_t)b * T_N;
    const int q_own = n0 + wv_ * 16 + col;   // this lane's query

    // Q B-frags from global: B[k=ch][n=q]: n=col -> q_own, k=s*32+quad*8+j
    f16x8 qh[2], ql[2];
    #pragma unroll
    for (int s = 0; s < 2; ++s) {
        const size_t qoff = (bN + q_own) * 64 + s * 32 + quad * 8;
        qh[s] = *(const f16x8*)&qt_hi[qoff];
        ql[s] = *(const f16x8*)&qt_lo[qoff];
    }

    f32x4 O[4];
    #pragma unroll
    for (int t = 0; t < 4; ++t) O[t] = (f32x4){0.f, 0.f, 0.f, 0.f};
    float m_st = -INFINITY, l_st = 0.f;

    for (int it = 0; it < TILES_PER_SLICE; ++it) {
        const int m0 = (slice * TILES_PER_SLICE + it) * 64;
        __syncthreads();   // previous iteration's ks/vs reads done
        for (int i = tid; i < 1024; i += 256) {
            if (i < 512) {
                const int row = i >> 3, cc = i & 7;
                *(float4*)&ks[row * 72 + cc * 8] =
                    *(const float4*)&kt[(bN + m0 + row) * 64 + cc * 8];
            } else {
                const int j = i - 512, row = j >> 3, cc = j & 7;
                *(float4*)&vs[row * 72 + cc * 8] =
                    *(const float4*)&vb[((size_t)(b * 64 + row)) * T_N + m0 + cc * 8];
            }
        }
        __syncthreads();

        // --- S^T = K Q^T: acc[t] = S^T[key=16t+quad*4+r][q=col] ---
        f32x4 acc[4];
        #pragma unroll
        for (int t = 0; t < 4; ++t) acc[t] = (f32x4){0.f, 0.f, 0.f, 0.f};
        #pragma unroll
        for (int s = 0; s < 2; ++s) {
            #pragma unroll
            for (int t = 0; t < 4; ++t) {
                const f16x8 kf =   // A[m=key][k=ch]: m=col -> key = 16t+col
                    *(const f16x8*)&ks[(t * 16 + col) * 72 + s * 32 + quad * 8];
                acc[t] = __builtin_amdgcn_mfma_f32_16x16x32_f16(kf, qh[s], acc[t], 0, 0, 0);
                acc[t] = __builtin_amdgcn_mfma_f32_16x16x32_f16(kf, ql[s], acc[t], 0, 0, 0);
            }
        }

        // --- online softmax: row = q = col; reduce across quads only ---
        float mx = -INFINITY;
        #pragma unroll
        for (int t = 0; t < 4; ++t)
            #pragma unroll
            for (int r = 0; r < 4; ++r) mx = fmaxf(mx, acc[t][r]);
        mx = fmaxf(mx, __shfl_xor(mx, 16));
        mx = fmaxf(mx, __shfl_xor(mx, 32));
        const float mnew = fmaxf(m_st, mx);
        const float alpha = __expf(m_st - mnew);
        float sum = 0.f;
        f16x4 pf[4];
        #pragma unroll
        for (int t = 0; t < 4; ++t) {
            #pragma unroll
            for (int r = 0; r < 4; ++r) {
                const float pv = __expf(acc[t][r] - mnew);
                sum += pv;
                pf[t][r] = (_Float16)pv;   // B[k=key=16t+quad*4+r][n=q=col]
            }
        }
        sum += __shfl_xor(sum, 16);
        sum += __shfl_xor(sum, 32);
        l_st = alpha * l_st + sum;
        m_st = mnew;

        // --- O = alpha*O + V P^T via 16x16x16 MFMA (P in registers) ---
        #pragma unroll
        for (int tc = 0; tc < 4; ++tc) {
            O[tc] *= alpha;
            #pragma unroll
            for (int t = 0; t < 4; ++t) {
                const f16x4 vf =   // A[m=c][k=key]: m=col -> c = tc*16+col
                    *(const f16x4*)&vs[(tc * 16 + col) * 72 + t * 16 + quad * 4];
                O[tc] = __builtin_amdgcn_mfma_f32_16x16x16f16(vf, pf[t], O[tc], 0, 0, 0);
            }
        }
    }

    // --- epilogue: O[tc][r]: c = tc*16+quad*4+r, q = col ---
    #pragma unroll
    for (int tc = 0; tc < 4; ++tc) {
        #pragma unroll
        for (int r = 0; r < 4; ++r) {
            o_part[((size_t)((slice * T_B + b) * 64 + tc * 16 + quad * 4 + r)) * T_N +
                   q_own] = f2h(O[tc][r]);
        }
    }
    if (quad == 0) {
        const size_t off = (size_t)(slice * T_B + b) * T_N + q_own;
        mp[off] = m_st;
        lp[off] = l_st;
    }
}

// ---------------------------------------------------------------------------
// Kernel 3: combine slices. grid (N/32, B), 256 thr. Pure streaming.
// ---------------------------------------------------------------------------
__global__ __launch_bounds__(256) void combine_kernel(
    const unsigned short* __restrict__ o_part,
    const float* __restrict__ mp, const float* __restrict__ lp,
    float* __restrict__ out)
{
    __shared__ float wn[NSLICE][32];

    const int tid = threadIdx.x;
    const int n0  = blockIdx.x * 32;
    const int b   = blockIdx.y;

    if (tid < 32) {
        float m_s[NSLICE], l_s[NSLICE];
        #pragma unroll
        for (int s = 0; s < NSLICE; ++s) {
            const size_t off = (size_t)(s * T_B + b) * T_N + n0 + tid;
            m_s[s] = mp[off];
            l_s[s] = lp[off];
        }
        float M = m_s[0];
        #pragma unroll
        for (int s = 1; s < NSLICE; ++s) M = fmaxf(M, m_s[s]);
        float w_s[NSLICE], L = 0.f;
        #pragma unroll
        for (int s = 0; s < NSLICE; ++s) {
            w_s[s] = __expf(m_s[s] - M);
            L += l_s[s] * w_s[s];
        }
        const float inv = 1.f / L;
        #pragma unroll
        for (int s = 0; s < NSLICE; ++s) wn[s][tid] = w_s[s] * inv;
    }
    __syncthreads();

    for (int t = tid; t < 512; t += 256) {
        const int c = t >> 3, g = t & 7;
        float4 acc = make_float4(0.f, 0.f, 0.f, 0.f);
        #pragma unroll
        for (int s = 0; s < NSLICE; ++s) {
            const ushort4 o4 = *(const ushort4*)
                &o_part[((size_t)((s * T_B + b) * 64 + c)) * T_N + n0 + g * 4];
            acc.x = fmaf(h2f(o4.x), wn[s][g * 4 + 0], acc.x);
            acc.y = fmaf(h2f(o4.y), wn[s][g * 4 + 1], acc.y);
            acc.z = fmaf(h2f(o4.z), wn[s][g * 4 + 2], acc.z);
            acc.w = fmaf(h2f(o4.w), wn[s][g * 4 + 3], acc.w);
        }
        *(float4*)&out[((size_t)(b * 64 + c)) * T_N + n0 + g * 4] = acc;
    }
}

// ---------------------------------------------------------------------------
extern "C" void kernel_launch(void* const* d_in, const int* in_sizes, int n_in,
                              void* d_out, int out_size, void* d_ws, size_t ws_size,
                              hipStream_t stream) {
    const float* x  = (const float*)d_in[0];
    const float* Wq = (const float*)d_in[1];
    const float* bq = (const float*)d_in[2];
    const float* Wk = (const float*)d_in[3];
    const float* bk = (const float*)d_in[4];
    const float* Wv = (const float*)d_in[5];
    const float* bv = (const float*)d_in[6];
    float* outp = (float*)d_out;

    const size_t elems = (size_t)T_B * T_N * T_C;
    unsigned short* qt_hi  = (unsigned short*)d_ws;
    unsigned short* qt_lo  = qt_hi + elems;
    unsigned short* ktp    = qt_lo + elems;
    unsigned short* vbuf   = ktp + elems;
    unsigned short* o_part = vbuf + elems;                       // NSLICE*elems
    float* mp = (float*)(o_part + (size_t)NSLICE * elems);
    float* lp = mp + (size_t)NSLICE * T_B * T_N;

    qkv_kernel<<<dim3(T_N / 32, T_B), 256, 0, stream>>>(
        x, Wq, bq, Wk, bk, Wv, bv, qt_hi, qt_lo, ktp, vbuf);
    attn_kernel<<<dim3(T_N / 64, NSLICE, T_B), 256, 0, stream>>>(
        qt_hi, qt_lo, ktp, vbuf, o_part, mp, lp);
    combine_kernel<<<dim3(T_N / 32, T_B), 256, 0, stream>>>(
        o_part, mp, lp, outp);
}